// Round 3
// baseline (45.947 us; speedup 1.0000x reference)
//
#include <hip/hip_runtime.h>

#define TPB 256
#define IPT 8          // source points per thread (contiguous per thread)
#define NIB 2          // i-blocks: N / (TPB*IPT) = 4096/2048
#define NPTS 4096
#define NB 8

// Partial chamfer mins: grid = 2(dir) * NB * NIB * njb blocks (njb=64 -> 2048).
// Each block: stage tgt j-chunk (jchunk=64) into LDS as (x,y,z,||g||^2), each
// thread owns IPT contiguous source points (vector-loaded), computes
// min_j(gg - 2 p.g) over the chunk, writes mn + ||p||^2 to
// partial[(dir*NB+b)*njb + jb][i] via float4 stores.
// launch_bounds(256,6): 6 waves/EU -> 24 waves/CU, VGPR cap ~85.
__global__ __launch_bounds__(TPB, 6) void cd_partial_kernel(
    const float* __restrict__ pred, const float* __restrict__ gt,
    float* __restrict__ partial, float* __restrict__ out, int njb, int jchunk) {
  extern __shared__ float4 sg[];

  if (blockIdx.x == 0 && threadIdx.x == 0) *out = 0.0f;  // replaces memset dispatch

  int bid = blockIdx.x;
  int jb  = bid % njb;  bid /= njb;
  int ib  = bid & (NIB - 1); bid /= NIB;
  int b   = bid & (NB - 1);  bid /= NB;
  int dir = bid;  // 0: src=pred,tgt=gt ; 1: src=gt,tgt=pred

  const float* src = (dir == 0) ? pred : gt;
  const float* tgt = (dir == 0) ? gt : pred;
  src += (size_t)b * NPTS * 3;
  tgt += (size_t)b * NPTS * 3;

  const int t = threadIdx.x;

  // stage target chunk into LDS (jchunk=64 -> first 64 threads)
  for (int p = t; p < jchunk; p += TPB) {
    int j = jb * jchunk + p;
    float gx = tgt[j * 3 + 0];
    float gy = tgt[j * 3 + 1];
    float gz = tgt[j * 3 + 2];
    sg[p] = make_float4(gx, gy, gz, fmaf(gx, gx, fmaf(gy, gy, gz * gz)));
  }

  // vector-load my IPT contiguous source points: 24 floats = 6 x float4
  const int ibase = ib * (TPB * IPT);
  const float4* sv = (const float4*)(src + (size_t)(ibase + t * IPT) * 3);
  float4 A = sv[0], B2 = sv[1], C = sv[2], D = sv[3], E = sv[4], F = sv[5];
  float x[IPT], y[IPT], z[IPT];
  x[0]=A.x;  y[0]=A.y;  z[0]=A.z;
  x[1]=A.w;  y[1]=B2.x; z[1]=B2.y;
  x[2]=B2.z; y[2]=B2.w; z[2]=C.x;
  x[3]=C.y;  y[3]=C.z;  z[3]=C.w;
  x[4]=D.x;  y[4]=D.y;  z[4]=D.z;
  x[5]=D.w;  y[5]=E.x;  z[5]=E.y;
  x[6]=E.z;  y[6]=E.w;  z[6]=F.x;
  x[7]=F.y;  y[7]=F.z;  z[7]=F.w;

  float qx[IPT], qy[IPT], qz[IPT], pp[IPT], mn[IPT];
#pragma unroll
  for (int k = 0; k < IPT; ++k) {
    qx[k] = -2.0f * x[k];
    qy[k] = -2.0f * y[k];
    qz[k] = -2.0f * z[k];
    pp[k] = fmaf(x[k], x[k], fmaf(y[k], y[k], z[k] * z[k]));
    mn[k] = 3.4e38f;
  }
  __syncthreads();

  // main loop: per 2 j's per k: 6 FMA + 1 min3 = 7 VALU (3.5/pair)
#pragma unroll 4
  for (int p = 0; p < jchunk; p += 2) {
    float4 g0 = sg[p];
    float4 g1 = sg[p + 1];
#pragma unroll
    for (int k = 0; k < IPT; ++k) {
      float v0 = fmaf(qx[k], g0.x, fmaf(qy[k], g0.y, fmaf(qz[k], g0.z, g0.w)));
      float v1 = fmaf(qx[k], g1.x, fmaf(qy[k], g1.y, fmaf(qz[k], g1.z, g1.w)));
      mn[k] = fminf(mn[k], fminf(v0, v1));
    }
  }

  // vector store: 8 consecutive floats = 2 x float4
  float* outp = partial + ((size_t)((dir * NB + b) * njb + jb)) * NPTS + ibase + t * IPT;
  float4 s0 = make_float4(mn[0] + pp[0], mn[1] + pp[1], mn[2] + pp[2], mn[3] + pp[3]);
  float4 s1 = make_float4(mn[4] + pp[4], mn[5] + pp[5], mn[6] + pp[6], mn[7] + pp[7]);
  ((float4*)outp)[0] = s0;
  ((float4*)outp)[1] = s1;
}

// Reduce: for each (dir,b,i) take min over njb partials, sum all, /NB,
// atomicAdd into out (zeroed by cd_partial block 0, stream-ordered).
__global__ __launch_bounds__(TPB) void cd_reduce_kernel(
    const float* __restrict__ partial, float* __restrict__ out, int njb) {
  const int total = 2 * NB * NPTS;
  int tid = blockIdx.x * TPB + threadIdx.x;
  float local = 0.0f;
  for (int s = tid; s < total; s += gridDim.x * TPB) {
    int db = s >> 12;          // (dir*NB + b), since NPTS = 4096
    int i  = s & (NPTS - 1);
    const float* p = partial + (size_t)db * njb * NPTS + i;
    float m = p[0];
#pragma unroll 8
    for (int jb = 1; jb < njb; ++jb) m = fminf(m, p[(size_t)jb * NPTS]);
    local += m;
  }
  // wave reduce
#pragma unroll
  for (int off = 32; off > 0; off >>= 1) local += __shfl_down(local, off, 64);
  __shared__ float red[TPB / 64];
  int wave = threadIdx.x >> 6;
  int lane = threadIdx.x & 63;
  if (lane == 0) red[wave] = local;
  __syncthreads();
  if (threadIdx.x == 0) {
    float s = 0.0f;
    for (int w = 0; w < TPB / 64; ++w) s += red[w];
    atomicAdd(out, s * (1.0f / NB));
  }
}

extern "C" void kernel_launch(void* const* d_in, const int* in_sizes, int n_in,
                              void* d_out, int out_size, void* d_ws, size_t ws_size,
                              hipStream_t stream) {
  const float* pred = (const float*)d_in[0];
  const float* gt   = (const float*)d_in[1];
  float* out        = (float*)d_out;
  float* partial    = (float*)d_ws;

  // choose j-split count to fit workspace: need 2*NB*njb*NPTS floats
  int njb = 64;
  {
    size_t per_jb = (size_t)2 * NB * NPTS * sizeof(float);  // 256 KB per jb level
    size_t need = per_jb * njb;
    if (ws_size < need) {
      njb = (int)(ws_size / per_jb);
      if (njb < 1) njb = 1;
      while (njb & (njb - 1)) njb &= njb - 1;  // power of two so it divides 4096
      if (njb > 64) njb = 64;
    }
  }
  int jchunk = NPTS / njb;

  dim3 grid(2 * NB * NIB * njb);
  size_t lds = (size_t)jchunk * sizeof(float4);
  cd_partial_kernel<<<grid, TPB, lds, stream>>>(pred, gt, partial, out, njb, jchunk);
  cd_reduce_kernel<<<256, TPB, 0, stream>>>(partial, out, njb);
}

// Round 4
// 39.494 us; speedup vs baseline: 1.1634x; 1.1634x over previous
//
#include <hip/hip_runtime.h>

#define TPB 256
#define IPT 8          // source points per thread (contiguous per thread)
#define NIB 2          // i-blocks: N / (TPB*IPT) = 4096/2048
#define NPTS 4096
#define NB 8

typedef float v2f __attribute__((ext_vector_type(2)));

// packed f32 fma: d = a*b + c per 32-bit half (VOP3P, CDNA)
static __device__ __forceinline__ v2f pk_fma(v2f a, v2f b, v2f c) {
  v2f d;
  asm("v_pk_fma_f32 %0, %1, %2, %3" : "=v"(d) : "v"(a), "v"(b), "v"(c));
  return d;
}

// Partial chamfer mins: grid = 2(dir) * NB * NIB * njb blocks (njb=32 -> 1024).
// LDS holds the tgt j-chunk in PAIR-SoA: per j-pair two float4s:
//   spr[2p]   = (x0, x1, y0, y1)
//   spr[2p+1] = (z0, z1, w0, w1)   where w = ||g||^2
// Inner loop per pair per src point: 3 v_pk_fma_f32 + 1 v_min3_f32.
__global__ __launch_bounds__(TPB, 4) void cd_partial_kernel(
    const float* __restrict__ pred, const float* __restrict__ gt,
    float* __restrict__ partial, float* __restrict__ out, int njb, int jchunk) {
  extern __shared__ float4 spr[];

  if (blockIdx.x == 0 && threadIdx.x == 0) *out = 0.0f;  // replaces memset dispatch

  int bid = blockIdx.x;
  int jb  = bid % njb;  bid /= njb;
  int ib  = bid & (NIB - 1); bid /= NIB;
  int b   = bid & (NB - 1);  bid /= NB;
  int dir = bid;  // 0: src=pred,tgt=gt ; 1: src=gt,tgt=pred

  const float* src = (dir == 0) ? pred : gt;
  const float* tgt = (dir == 0) ? gt : pred;
  src += (size_t)b * NPTS * 3;
  tgt += (size_t)b * NPTS * 3;

  const int t = threadIdx.x;

  // stage target chunk into pair-SoA LDS (one thread per j)
  for (int j = t; j < jchunk; j += TPB) {
    int jj = jb * jchunk + j;
    float gx = tgt[jj * 3 + 0];
    float gy = tgt[jj * 3 + 1];
    float gz = tgt[jj * 3 + 2];
    float gw = fmaf(gx, gx, fmaf(gy, gy, gz * gz));
    int p = j >> 1, h = j & 1;
    float* base = (float*)&spr[2 * p];
    base[0 + h] = gx;
    base[2 + h] = gy;
    base[4 + h] = gz;
    base[6 + h] = gw;
  }

  // vector-load my IPT contiguous source points: 24 floats = 6 x float4
  const int ibase = ib * (TPB * IPT);
  const float4* sv = (const float4*)(src + (size_t)(ibase + t * IPT) * 3);
  float4 A = sv[0], B2 = sv[1], C = sv[2], D = sv[3], E = sv[4], F = sv[5];
  float x[IPT], y[IPT], z[IPT];
  x[0]=A.x;  y[0]=A.y;  z[0]=A.z;
  x[1]=A.w;  y[1]=B2.x; z[1]=B2.y;
  x[2]=B2.z; y[2]=B2.w; z[2]=C.x;
  x[3]=C.y;  y[3]=C.z;  z[3]=C.w;
  x[4]=D.x;  y[4]=D.y;  z[4]=D.z;
  x[5]=D.w;  y[5]=E.x;  z[5]=E.y;
  x[6]=E.z;  y[6]=E.w;  z[6]=F.x;
  x[7]=F.y;  y[7]=F.z;  z[7]=F.w;

  v2f qx2[IPT], qy2[IPT], qz2[IPT];
  float pp[IPT], mn[IPT];
#pragma unroll
  for (int k = 0; k < IPT; ++k) {
    float qx = -2.0f * x[k], qy = -2.0f * y[k], qz = -2.0f * z[k];
    qx2[k] = (v2f){qx, qx};
    qy2[k] = (v2f){qy, qy};
    qz2[k] = (v2f){qz, qz};
    pp[k] = fmaf(x[k], x[k], fmaf(y[k], y[k], z[k] * z[k]));
    mn[k] = 3.4e38f;
  }
  __syncthreads();

  // main loop over j-pairs: 2 broadcast ds_read_b128 + IPT*(3 pk_fma + 1 min3)
  const int npair = jchunk >> 1;
#pragma unroll 8
  for (int p = 0; p < npair; ++p) {
    float4 u = spr[2 * p];        // (x0,x1,y0,y1)
    float4 w = spr[2 * p + 1];    // (z0,z1,w0,w1)
    v2f X = (v2f){u.x, u.y};
    v2f Y = (v2f){u.z, u.w};
    v2f Z = (v2f){w.x, w.y};
    v2f W = (v2f){w.z, w.w};
#pragma unroll
    for (int k = 0; k < IPT; ++k) {
      v2f acc = pk_fma(qz2[k], Z, W);
      acc = pk_fma(qy2[k], Y, acc);
      acc = pk_fma(qx2[k], X, acc);
      mn[k] = fminf(mn[k], fminf(acc.x, acc.y));  // v_min3_f32
    }
  }

  // vector store: 8 consecutive floats = 2 x float4
  float* outp = partial + ((size_t)((dir * NB + b) * njb + jb)) * NPTS + ibase + t * IPT;
  float4 s0 = make_float4(mn[0] + pp[0], mn[1] + pp[1], mn[2] + pp[2], mn[3] + pp[3]);
  float4 s1 = make_float4(mn[4] + pp[4], mn[5] + pp[5], mn[6] + pp[6], mn[7] + pp[7]);
  ((float4*)outp)[0] = s0;
  ((float4*)outp)[1] = s1;
}

// Reduce: for each (dir,b,i) take min over njb partials, sum all, /NB,
// atomicAdd into out (zeroed by cd_partial block 0, stream-ordered).
__global__ __launch_bounds__(TPB) void cd_reduce_kernel(
    const float* __restrict__ partial, float* __restrict__ out, int njb) {
  const int total = 2 * NB * NPTS;
  int tid = blockIdx.x * TPB + threadIdx.x;
  float local = 0.0f;
  for (int s = tid; s < total; s += gridDim.x * TPB) {
    int db = s >> 12;          // (dir*NB + b), since NPTS = 4096
    int i  = s & (NPTS - 1);
    const float* p = partial + (size_t)db * njb * NPTS + i;
    float m = p[0];
#pragma unroll 8
    for (int jb = 1; jb < njb; ++jb) m = fminf(m, p[(size_t)jb * NPTS]);
    local += m;
  }
  // wave reduce
#pragma unroll
  for (int off = 32; off > 0; off >>= 1) local += __shfl_down(local, off, 64);
  __shared__ float red[TPB / 64];
  int wave = threadIdx.x >> 6;
  int lane = threadIdx.x & 63;
  if (lane == 0) red[wave] = local;
  __syncthreads();
  if (threadIdx.x == 0) {
    float s = 0.0f;
    for (int w = 0; w < TPB / 64; ++w) s += red[w];
    atomicAdd(out, s * (1.0f / NB));
  }
}

extern "C" void kernel_launch(void* const* d_in, const int* in_sizes, int n_in,
                              void* d_out, int out_size, void* d_ws, size_t ws_size,
                              hipStream_t stream) {
  const float* pred = (const float*)d_in[0];
  const float* gt   = (const float*)d_in[1];
  float* out        = (float*)d_out;
  float* partial    = (float*)d_ws;

  // choose j-split count to fit workspace: need 2*NB*njb*NPTS floats
  int njb = 32;
  {
    size_t per_jb = (size_t)2 * NB * NPTS * sizeof(float);  // 256 KB per jb level
    size_t need = per_jb * njb;
    if (ws_size < need) {
      njb = (int)(ws_size / per_jb);
      if (njb < 1) njb = 1;
      while (njb & (njb - 1)) njb &= njb - 1;  // power of two so it divides 4096
      if (njb > 32) njb = 32;
    }
  }
  int jchunk = NPTS / njb;

  dim3 grid(2 * NB * NIB * njb);
  size_t lds = (size_t)jchunk * sizeof(float4);
  cd_partial_kernel<<<grid, TPB, lds, stream>>>(pred, gt, partial, out, njb, jchunk);
  cd_reduce_kernel<<<256, TPB, 0, stream>>>(partial, out, njb);
}